// Round 3
// baseline (502.563 us; speedup 1.0000x reference)
//
#include <hip/hip_runtime.h>
#include <math.h>

#define BB 16
#define SS 4096
#define HH 1024
#define CC 64

typedef __attribute__((ext_vector_type(4))) float f32x4;
typedef __attribute__((ext_vector_type(8))) short s16x8;

__device__ __forceinline__ ushort f2bf(float x) {
    union { float f; unsigned u; } un; un.f = x;
    unsigned r = (un.u + 0x7FFFu + ((un.u >> 16) & 1u)) >> 16;
    return (ushort)r;
}
__device__ __forceinline__ float bf2f(ushort h) {
    union { unsigned u; float f; } un; un.u = ((unsigned)h) << 16; return un.f;
}

// ---------------- prep: querys -> hi/lo bf16
__global__ __launch_bounds__(256) void prep_querys_kernel(
    const float* __restrict__ q, ushort* __restrict__ qhi, ushort* __restrict__ qlo)
{
    const int i4 = blockIdx.x * 256 + threadIdx.x;   // float4 index, 16384 total
    const float4 v = ((const float4*)q)[i4];
    ushort4 h, l;
    h.x = f2bf(v.x); l.x = f2bf(v.x - bf2f(h.x));
    h.y = f2bf(v.y); l.y = f2bf(v.y - bf2f(h.y));
    h.z = f2bf(v.z); l.z = f2bf(v.z - bf2f(h.z));
    h.w = f2bf(v.w); l.w = f2bf(v.w - bf2f(h.w));
    ((ushort4*)qhi)[i4] = h;
    ((ushort4*)qlo)[i4] = l;
}

// ---------------- scores: LDS-free. Each wave owns a 16s x 64c tile.
// A-frags (hidden) loaded straight from global in MFMA layout (2x float4/lane),
// converted to hi/lo bf16 in registers. B-frags (querys hi/lo) loaded straight
// from global (L1/L2-resident, shared by all waves). 3-MFMA split product.
__global__ __launch_bounds__(256) void scores_kernel(
    const float* __restrict__ hidden, const ushort* __restrict__ qhi,
    const ushort* __restrict__ qlo, float* __restrict__ scores)
{
    const int b = blockIdx.y, t = threadIdx.x;
    const int w = t >> 6, lane = t & 63, col = lane & 15, quad = lane >> 4;
    const int s0 = blockIdx.x * 64 + w * 16;

    const float*  arow = hidden + ((size_t)b * SS + s0 + col) * HH + quad * 8;
    const ushort* qh0  = qhi + (size_t)col * HH + quad * 8;
    const ushort* ql0  = qlo + (size_t)col * HH + quad * 8;

    f32x4 acc[4];
#pragma unroll
    for (int nt = 0; nt < 4; ++nt) acc[nt] = (f32x4){0.f, 0.f, 0.f, 0.f};

    float4 a0 = *(const float4*)arow;
    float4 a1 = *(const float4*)(arow + 4);

    for (int k0 = 0; k0 < HH; k0 += 32) {
        s16x8 bh[4], bl[4];
#pragma unroll
        for (int nt = 0; nt < 4; ++nt) {
            bh[nt] = *(const s16x8*)(qh0 + (size_t)nt * 16 * HH + k0);
            bl[nt] = *(const s16x8*)(ql0 + (size_t)nt * 16 * HH + k0);
        }
        const float af[8] = {a0.x, a0.y, a0.z, a0.w, a1.x, a1.y, a1.z, a1.w};
        s16x8 ah, al;
#pragma unroll
        for (int j = 0; j < 8; ++j) {
            const ushort h = f2bf(af[j]);
            ah[j] = (short)h;
            al[j] = (short)f2bf(af[j] - bf2f(h));
        }
        if (k0 + 32 < HH) {                 // prefetch next A chunk
            a0 = *(const float4*)(arow + k0 + 32);
            a1 = *(const float4*)(arow + k0 + 36);
        }
#pragma unroll
        for (int nt = 0; nt < 4; ++nt) {
            acc[nt] = __builtin_amdgcn_mfma_f32_16x16x32_bf16(ah, bh[nt], acc[nt], 0, 0, 0);
            acc[nt] = __builtin_amdgcn_mfma_f32_16x16x32_bf16(ah, bl[nt], acc[nt], 0, 0, 0);
            acc[nt] = __builtin_amdgcn_mfma_f32_16x16x32_bf16(al, bh[nt], acc[nt], 0, 0, 0);
        }
    }
    // C/D: n(col)=c within n-tile, m(quad*4+reg)=s within this wave's 16-row tile
#pragma unroll
    for (int nt = 0; nt < 4; ++nt) {
        const int c = nt * 16 + col;
        *(f32x4*)&scores[((size_t)(b * CC + c)) * SS + s0 + quad * 4] = acc[nt];
    }
}

// ---------------- softmax over s, writes bf16 factor
__global__ __launch_bounds__(256) void softmax_kernel(
    const float* __restrict__ scores, ushort* __restrict__ factor)
{
    const float* p = scores + (size_t)blockIdx.x * SS;
    ushort* f = factor + (size_t)blockIdx.x * SS;
    const int t = threadIdx.x;
    float4 v[4];
    float m = -3.0e38f;
#pragma unroll
    for (int i = 0; i < 4; ++i) {
        v[i] = *(const float4*)&p[t * 4 + i * 1024];
        m = fmaxf(m, fmaxf(fmaxf(v[i].x, v[i].y), fmaxf(v[i].z, v[i].w)));
    }
#pragma unroll
    for (int off = 1; off < 64; off <<= 1) m = fmaxf(m, __shfl_xor(m, off));
    __shared__ float redm[4];
    __shared__ float reds[4];
    const int wave = t >> 6, lane = t & 63;
    if (lane == 0) redm[wave] = m;
    __syncthreads();
    m = fmaxf(fmaxf(redm[0], redm[1]), fmaxf(redm[2], redm[3]));

    float sum = 0.0f;
#pragma unroll
    for (int i = 0; i < 4; ++i) {
        v[i].x = __expf(v[i].x - m); v[i].y = __expf(v[i].y - m);
        v[i].z = __expf(v[i].z - m); v[i].w = __expf(v[i].w - m);
        sum += (v[i].x + v[i].y) + (v[i].z + v[i].w);
    }
#pragma unroll
    for (int off = 1; off < 64; off <<= 1) sum += __shfl_xor(sum, off);
    if (lane == 0) reds[wave] = sum;
    __syncthreads();
    sum = (reds[0] + reds[1]) + (reds[2] + reds[3]);
    const float inv = 1.0f / sum;
#pragma unroll
    for (int i = 0; i < 4; ++i) {
        ushort4 o;
        o.x = f2bf(v[i].x * inv); o.y = f2bf(v[i].y * inv);
        o.z = f2bf(v[i].z * inv); o.w = f2bf(v[i].w * inv);
        ((ushort4*)f)[t + i * 256] = o;
    }
}

// ---------------- pool: parts[ks][b][c][h] via bf16 MFMA, 64c x 64h tile, split-8 over S
#define KSPLIT 8
__global__ __launch_bounds__(256) void pool_kernel(
    const float* __restrict__ hidden, const ushort* __restrict__ factor,
    float* __restrict__ parts)
{
    __shared__ __align__(16) ushort Ht[64][72];  // [h][s], s contiguous

    const int b  = blockIdx.y;
    const int h0 = blockIdx.x * 64;
    const int ks = blockIdx.z;
    const int sbeg = ks * (SS / KSPLIT);
    const int t = threadIdx.x;
    const int w = t >> 6, lane = t & 63, col = lane & 15, quad = lane >> 4;
    const int hc = t & 15;
    const int sq = t >> 4;   // 0..15

    f32x4 acc[4];
#pragma unroll
    for (int j = 0; j < 4; ++j) acc[j] = (f32x4){0.f, 0.f, 0.f, 0.f};

    const float* hbase = hidden + (size_t)b * SS * HH + h0;
    const ushort* fbase = factor + (size_t)(b * CC + w * 16 + col) * SS + sbeg;

    float v[16];
#pragma unroll
    for (int pp = 0; pp < 2; ++pp)
#pragma unroll
        for (int mm = 0; mm < 4; ++mm)
#pragma unroll
            for (int e = 0; e < 2; ++e)
                v[pp * 8 + mm * 2 + e] =
                    hbase[(size_t)(sbeg + 2 * (sq + 16 * pp) + e) * HH + hc + 16 * mm];

    for (int sc = 0; sc < SS / KSPLIT; sc += 64) {
        __syncthreads();
#pragma unroll
        for (int pp = 0; pp < 2; ++pp)
#pragma unroll
            for (int mm = 0; mm < 4; ++mm) {
                unsigned pack = (unsigned)f2bf(v[pp * 8 + mm * 2 + 0]) |
                                ((unsigned)f2bf(v[pp * 8 + mm * 2 + 1]) << 16);
                ((unsigned*)Ht)[(hc + 16 * mm) * 36 + (sq + 16 * pp)] = pack;
            }
        __syncthreads();

        const s16x8 fa0 = *(const s16x8*)&fbase[sc + quad * 8];
        const s16x8 fa1 = *(const s16x8*)&fbase[sc + 32 + quad * 8];

        if (sc + 64 < SS / KSPLIT) {
#pragma unroll
            for (int pp = 0; pp < 2; ++pp)
#pragma unroll
                for (int mm = 0; mm < 4; ++mm)
#pragma unroll
                    for (int e = 0; e < 2; ++e)
                        v[pp * 8 + mm * 2 + e] =
                            hbase[(size_t)(sbeg + sc + 64 + 2 * (sq + 16 * pp) + e) * HH + hc + 16 * mm];
        }

#pragma unroll
        for (int ksp = 0; ksp < 2; ++ksp) {
            const s16x8 fa = ksp ? fa1 : fa0;
#pragma unroll
            for (int nt = 0; nt < 4; ++nt) {
                const s16x8 hb = *(const s16x8*)&Ht[nt * 16 + col][ksp * 32 + quad * 8];
                acc[nt] = __builtin_amdgcn_mfma_f32_16x16x32_bf16(fa, hb, acc[nt], 0, 0, 0);
            }
        }
    }

    float* dst = parts + (size_t)ks * (BB * CC * HH) + (size_t)b * (CC * HH);
#pragma unroll
    for (int nt = 0; nt < 4; ++nt) {
        const int h = h0 + nt * 16 + col;
#pragma unroll
        for (int r = 0; r < 4; ++r) {
            const int c = w * 16 + quad * 4 + r;
            dst[(size_t)c * HH + h] = acc[nt][r];
        }
    }
}

// ---------------- final reduce of 8 split-K partials
__global__ __launch_bounds__(256) void reduce8_kernel(
    const float* __restrict__ parts, float* __restrict__ out)
{
    const int i = blockIdx.x * 256 + threadIdx.x;   // float4 index, 262144 total
    const float4* p = (const float4*)parts;
    float4 r = {0.f, 0.f, 0.f, 0.f};
#pragma unroll
    for (int j = 0; j < KSPLIT; ++j) {
        const float4 a = p[i + (size_t)j * 262144];
        r.x += a.x; r.y += a.y; r.z += a.z; r.w += a.w;
    }
    ((float4*)out)[i] = r;
}

extern "C" void kernel_launch(void* const* d_in, const int* in_sizes, int n_in,
                              void* d_out, int out_size, void* d_ws, size_t ws_size,
                              hipStream_t stream)
{
    const float* hidden = (const float*)d_in[0];   // [16,4096,1024] fp32
    const float* querys = (const float*)d_in[1];   // [64,1024] fp32
    float* out = (float*)d_out;

    float*  scores = (float*)d_ws;                           // 16 MiB [0,16M)
    ushort* factor = (ushort*)((char*)d_ws + (16u << 20));   // 8 MiB [16M,24M)
    ushort* qhi    = (ushort*)((char*)d_ws + (24u << 20));   // 128 KiB
    ushort* qlo    = qhi + CC * HH;                          // 128 KiB
    float*  parts  = (float*)((char*)d_ws + (32u << 20));    // 32 MiB [32M,64M)

    prep_querys_kernel<<<dim3(CC * HH / 1024), 256, 0, stream>>>(querys, qhi, qlo);
    scores_kernel<<<dim3(SS / 64, BB), 256, 0, stream>>>(hidden, qhi, qlo, scores);
    softmax_kernel<<<dim3(BB * CC), 256, 0, stream>>>(scores, factor);
    pool_kernel<<<dim3(HH / 64, BB, KSPLIT), 256, 0, stream>>>(hidden, factor, parts);
    reduce8_kernel<<<dim3(1024), 256, 0, stream>>>(parts, out);
}